// Round 5
// baseline (15938.649 us; speedup 1.0000x reference)
//
#include <hip/hip_runtime.h>

typedef unsigned int       uint;
typedef unsigned short     ushort;
typedef unsigned long long ull;

#define NINP    512
#define NHID    1024
#define T_STEPS 512
#define B_SZ    64
#define KTOT    1536                 // NINP + NHID fused K
#define BN      (B_SZ * NHID)        // 65536

typedef __attribute__((ext_vector_type(8))) short bf16x8;
typedef __attribute__((ext_vector_type(4))) float f32x4;
typedef __attribute__((ext_vector_type(4))) uint  uintx4;

// ---------------- ws layout (bytes) ----------------
// Tagged state: ull per element = {packed hi|lo bf16 (low), tag (high)}.
#define WCOMB_BYTES (3 * NHID * KTOT * 2)            // 9,437,184
#define WS_BSUM     (WCOMB_BYTES)                    // f32 [3][1024]
#define WS_HP2      (WS_BSUM + 3 * NHID * 4)         // ull [64][1024] h    (tag t+1 after step t; h0 tag 0)
#define WS_RHP2     (WS_HP2 + BN * 8)                // ull [64][1024] r*h  (tag t+1 for step t)
#define WS_NEED     (WS_RHP2 + BN * 8)               // ~10.0 MB

__device__ __forceinline__ float sigmoidf_(float x) { return 1.0f / (1.0f + __expf(-x)); }
__device__ __forceinline__ float tanhf_(float x)    { return 1.0f - 2.0f / (__expf(2.0f * x) + 1.0f); }

__device__ __forceinline__ ushort bf16_rne(float f) {
    uint u = __float_as_uint(f);
    return (ushort)((u + 0x7FFFu + ((u >> 16) & 1u)) >> 16);
}
__device__ __forceinline__ float bf16_to_f(ushort s) { return __uint_as_float(((uint)s) << 16); }
__device__ __forceinline__ bf16x8 ld8(const ushort* p) { return *(const bf16x8*)p; }
__device__ __forceinline__ bf16x8 cvt8(const float* p) {
    float4 a = *(const float4*)p;
    float4 b = *(const float4*)(p + 4);
    bf16x8 r;
    r[0] = (short)bf16_rne(a.x); r[1] = (short)bf16_rne(a.y);
    r[2] = (short)bf16_rne(a.z); r[3] = (short)bf16_rne(a.w);
    r[4] = (short)bf16_rne(b.x); r[5] = (short)bf16_rne(b.y);
    r[6] = (short)bf16_rne(b.z); r[7] = (short)bf16_rne(b.w);
    return r;
}
__device__ __forceinline__ f32x4 zero4() { f32x4 z = {0.f, 0.f, 0.f, 0.f}; return z; }
#define MFMA(a, b, c) __builtin_amdgcn_mfma_f32_16x16x32_bf16((a), (b), (c), 0, 0, 0)

__device__ __forceinline__ uint ld_rlx(const uint* p) {
    return __hip_atomic_load(p, __ATOMIC_RELAXED, __HIP_MEMORY_SCOPE_AGENT);
}
// atomic 8B state store: value+tag land together at the MALL (no drain, no flag)
__device__ __forceinline__ void st_state(ull* p, uint val, uint tag) {
    ull v = (ull)val | ((ull)tag << 32);
    __hip_atomic_store(p, v, __ATOMIC_RELAXED, __HIP_MEMORY_SCOPE_AGENT);
}
__device__ __forceinline__ uint pack_hl(float v) {
    ushort hi = bf16_rne(v);
    ushort lo = bf16_rne(v - bf16_to_f(hi));
    return (uint)hi | ((uint)lo << 16);
}

// ---- tagged speculative load: 32 elements (4 k-slots x 8) = 16 dwordx4 ----
// b points at element (arow, wv*32 + q8); slots s at +256*s elements (2048B).
// Retry until ALL 32 tags >= target. Data is valid on exit (8B pair atomicity:
// a fresh tag in a pair implies its value dword is fresh too).
__device__ __forceinline__ void poll_load(const ull* b, uint target, uintx4 q[4][4]) {
    const uint* p0 = (const uint*)b;
    const uint* p1 = (const uint*)(b + 512);
    for (;;) {
        asm volatile("global_load_dwordx4 %0, %1, off sc0 sc1"             : "=v"(q[0][0]) : "v"(p0) : "memory");
        asm volatile("global_load_dwordx4 %0, %1, off offset:16 sc0 sc1"   : "=v"(q[0][1]) : "v"(p0) : "memory");
        asm volatile("global_load_dwordx4 %0, %1, off offset:32 sc0 sc1"   : "=v"(q[0][2]) : "v"(p0) : "memory");
        asm volatile("global_load_dwordx4 %0, %1, off offset:48 sc0 sc1"   : "=v"(q[0][3]) : "v"(p0) : "memory");
        asm volatile("global_load_dwordx4 %0, %1, off offset:2048 sc0 sc1" : "=v"(q[1][0]) : "v"(p0) : "memory");
        asm volatile("global_load_dwordx4 %0, %1, off offset:2064 sc0 sc1" : "=v"(q[1][1]) : "v"(p0) : "memory");
        asm volatile("global_load_dwordx4 %0, %1, off offset:2080 sc0 sc1" : "=v"(q[1][2]) : "v"(p0) : "memory");
        asm volatile("global_load_dwordx4 %0, %1, off offset:2096 sc0 sc1" : "=v"(q[1][3]) : "v"(p0) : "memory");
        asm volatile("global_load_dwordx4 %0, %1, off sc0 sc1"             : "=v"(q[2][0]) : "v"(p1) : "memory");
        asm volatile("global_load_dwordx4 %0, %1, off offset:16 sc0 sc1"   : "=v"(q[2][1]) : "v"(p1) : "memory");
        asm volatile("global_load_dwordx4 %0, %1, off offset:32 sc0 sc1"   : "=v"(q[2][2]) : "v"(p1) : "memory");
        asm volatile("global_load_dwordx4 %0, %1, off offset:48 sc0 sc1"   : "=v"(q[2][3]) : "v"(p1) : "memory");
        asm volatile("global_load_dwordx4 %0, %1, off offset:2048 sc0 sc1" : "=v"(q[3][0]) : "v"(p1) : "memory");
        asm volatile("global_load_dwordx4 %0, %1, off offset:2064 sc0 sc1" : "=v"(q[3][1]) : "v"(p1) : "memory");
        asm volatile("global_load_dwordx4 %0, %1, off offset:2080 sc0 sc1" : "=v"(q[3][2]) : "v"(p1) : "memory");
        asm volatile("global_load_dwordx4 %0, %1, off offset:2096 sc0 sc1" : "=v"(q[3][3]) : "v"(p1) : "memory");
        asm volatile("s_waitcnt vmcnt(0)" ::: "memory");
        uint mn = 0xFFFFFFFFu;
        #pragma unroll
        for (int s = 0; s < 4; ++s)
            #pragma unroll
            for (int r = 0; r < 4; ++r) {
                uint t0 = q[s][r][1], t1 = q[s][r][3];
                mn = mn < t0 ? mn : t0;
                mn = mn < t1 ? mn : t1;
            }
        if (__all(mn >= target)) break;
        __builtin_amdgcn_s_sleep(1);
    }
    __builtin_amdgcn_sched_barrier(0);
}
// extract bf16 frags from 8 tagged pairs of one k-slot (vals at [0],[2])
__device__ __forceinline__ bf16x8 hi_frag4(const uintx4* q) {
    uintx4 r;
    r[0] = __builtin_amdgcn_perm(q[0][2], q[0][0], 0x05040100u);
    r[1] = __builtin_amdgcn_perm(q[1][2], q[1][0], 0x05040100u);
    r[2] = __builtin_amdgcn_perm(q[2][2], q[2][0], 0x05040100u);
    r[3] = __builtin_amdgcn_perm(q[3][2], q[3][0], 0x05040100u);
    return *(bf16x8*)&r;
}
__device__ __forceinline__ bf16x8 lo_frag4(const uintx4* q) {
    uintx4 r;
    r[0] = __builtin_amdgcn_perm(q[0][2], q[0][0], 0x07060302u);
    r[1] = __builtin_amdgcn_perm(q[1][2], q[1][0], 0x07060302u);
    r[2] = __builtin_amdgcn_perm(q[2][2], q[2][0], 0x07060302u);
    r[3] = __builtin_amdgcn_perm(q[3][2], q[3][0], 0x07060302u);
    return *(bf16x8*)&r;
}

// ---------------- prep: weights -> fused bf16 layout ----------------
__global__ __launch_bounds__(256) void prep_w(
    const float* __restrict__ Wiz, const float* __restrict__ Wir, const float* __restrict__ Wih,
    const float* __restrict__ Whz, const float* __restrict__ Whr, const float* __restrict__ Whh,
    ushort* __restrict__ wcomb)
{
    int tid = blockIdx.x * 256 + threadIdx.x;
    int oct = tid % (KTOT / 8);
    int row = tid / (KTOT / 8);                      // gate*1024 + n
    int gate = row >> 10, n = row & 1023;
    int k0 = oct * 8;
    const float* src; int off;
    if (k0 < NINP) { src = gate == 0 ? Wiz : (gate == 1 ? Wir : Wih); off = n * NINP + k0; }
    else           { src = gate == 0 ? Whz : (gate == 1 ? Whr : Whh); off = n * NHID + (k0 - NINP); }
    ushort* dst = wcomb + (size_t)row * KTOT + k0;
    #pragma unroll
    for (int j = 0; j < 8; ++j) dst[j] = bf16_rne(src[off + j]);
}

// ---------------- prep: tagged h0 / rh init, bias sums ----------------
__global__ __launch_bounds__(256) void prep_misc(
    const float* __restrict__ h0,
    const float* __restrict__ biz, const float* __restrict__ bir, const float* __restrict__ bih,
    const float* __restrict__ bhz, const float* __restrict__ bhr, const float* __restrict__ bhh,
    ull* __restrict__ hp2, ull* __restrict__ rhp2, float* __restrict__ bsum)
{
    if (blockIdx.x < 256) {
        int i = blockIdx.x * 256 + threadIdx.x;
        hp2[i]  = (ull)pack_hl(h0[i]);               // tag 0
        rhp2[i] = 0ull;                              // tag 0 (consumers need >=1)
    } else {
        for (int n = threadIdx.x; n < NHID; n += 256) {
            bsum[n]            = biz[n] + bhz[n];
            bsum[NHID + n]     = bir[n] + bhr[n];
            bsum[2 * NHID + n] = bih[n] + bhh[n];
        }
    }
}

// ---------------- persistent GRU: 256 blocks x 512 threads, tag-in-data -----
// Block = (nt, mt): n-cols [nt*16,+16), batch rows [mt*16,+16). 8 waves split
// fused K=1536: wave wv does K-steps j = wv + 8s (s=0..5; s<2 x, s>=2 h).
// State elements carry their generation tag in the same atomic 8B word, so
// producer->consumer latency is ONE MALL round-trip: producers just store
// (no drain, no flag); consumers speculatively load + validate tags, retry.
// tag(h after step t) = t+1 (h0 = 0); tag(rh of step t) = t+1.
// Phase-1 consumer target: t.  Phase-2 consumer target: t+1.
// Reduce/elementwise tail is split 4-ways: wave w (w<4) owns batch-row group
// i=w (rows mbase+quad*4+w): r-reduce -> rh store, z-reduce -> zsig_w, then
// c-reduce -> h update -> hp + out stores. All four quarters publish in
// parallel; per-element tags make partial publication safe.
// lds_acc1 parity-double-buffered (fast-wave re-entry can precede slow-wave
// z-reduce); lds_acc2 single (rewrite gated through all gang blocks' phase-1
// polls, which need this block's hp stores, which follow the c-reduce reads).
__global__ __launch_bounds__(512, 1) void gru_persist(
    const float* __restrict__ x, const float* __restrict__ h0,
    const void* __restrict__ lengths_raw,
    const ushort* __restrict__ wcomb, const float* __restrict__ bsum,
    ull* __restrict__ hp2, ull* __restrict__ rhp2,
    float* __restrict__ out)
{
    const int bid = blockIdx.x;
    const int nt = bid >> 2, mt = bid & 3;
    const int nbase = nt * 16, mbase = mt * 16;
    const int tid = threadIdx.x;
    const int wv = tid >> 6, lane = tid & 63;
    const int col = lane & 15, quad = lane >> 4;
    const int q8 = quad * 8;

    __shared__ f32x4 lds_acc1[2][8][2][64];          // 32 KB (z,r partials, parity)
    __shared__ f32x4 lds_acc2[8][64];                // 8 KB  (c partials)
    __shared__ uint  lds_pad[11264];                 // 44 KB -> 84 KB total -> 1 block/CU
    lds_pad[tid & 1023] = tid;                       // keep pad live

    // ---- weight fragments -> VGPRs (once): 6 K-steps x 3 gates ----
    bf16x8 wfz[6], wfr[6], wfc[6];
    #pragma unroll
    for (int s = 0; s < 6; ++s) {
        const int j = wv + 8 * s;                    // K-step 0..47
        const size_t ko = (size_t)j * 32 + q8;
        wfz[s] = ld8(wcomb + (size_t)(0 * NHID + nbase + col) * KTOT + ko);
        wfr[s] = ld8(wcomb + (size_t)(1 * NHID + nbase + col) * KTOT + ko);
        wfc[s] = ld8(wcomb + (size_t)(2 * NHID + nbase + col) * KTOT + ko);
    }

    // wave w<4 owns batch-row group i=w: row_w = mbase + quad*4 + w
    const int row_w = mbase + quad * 4 + (wv & 3);
    const size_t gi_w = (size_t)row_w * NHID + nbase + col;
    const int* l32 = (const int*)lengths_raw;
    const bool is64 = (l32[1] == 0);
    int   len_w  = 0;
    float h_w    = 0.f;
    float zsig_w = 0.f;
    if (wv < 4) {
        len_w = is64 ? (int)((const long long*)lengths_raw)[row_w] : l32[row_w];
        h_w   = h0[gi_w];
    }

    const float bias_z = bsum[nbase + col];
    const float bias_r = bsum[NHID + nbase + col];
    const float bias_c = bsum[2 * NHID + nbase + col];

    const size_t arow = (size_t)(mbase + col);       // A-operand row (batch)
    const ull* hb = hp2  + arow * NHID + wv * 32 + q8;   // phase-1 load base
    const ull* rb = rhp2 + arow * NHID + wv * 32 + q8;   // phase-2 load base

    bf16x8 xf[2];

    // prologue: t=0 x-region
    f32x4 az = zero4(), ar = zero4();
    #pragma unroll
    for (int s = 0; s < 2; ++s) {
        const int k = (wv + 8 * s) * 32;
        xf[s] = cvt8(x + arow * NINP + k + q8);
        az = MFMA(xf[s], wfz[s], az);
        ar = MFMA(xf[s], wfr[s], ar);
    }

    for (int t = 0; t < T_STEPS; ++t) {
        const int par = t & 1;
        // ================= phase 1: z, r (h region) =================
        {
            uintx4 q[4][4];
            poll_load(hb, (uint)t, q);               // h(t-1): tags >= t
            #pragma unroll
            for (int s = 0; s < 4; ++s) {
                const bf16x8 hi = hi_frag4(q[s]);
                const bf16x8 lo = lo_frag4(q[s]);
                az = MFMA(hi, wfz[s + 2], az);
                ar = MFMA(hi, wfr[s + 2], ar);
                az = MFMA(lo, wfz[s + 2], az);
                ar = MFMA(lo, wfr[s + 2], ar);
            }
        }
        lds_acc1[par][wv][0][lane] = az;
        lds_acc1[par][wv][1][lane] = ar;
        __syncthreads();                             // phase-1 hand-off
        if (wv < 4) {
            // critical path: r-reduce(i=wv) -> rh -> tagged store
            const float* pr = ((const float*)&lds_acc1[par][0][1][lane]) + wv;
            float rs = bias_r;
            #pragma unroll
            for (int wp = 0; wp < 8; ++wp) rs += pr[wp * 512];
            st_state(&rhp2[gi_w], pack_hl(sigmoidf_(rs) * h_w), (uint)(t + 1));
            // z-reduce off the critical path
            const float* pz = ((const float*)&lds_acc1[par][0][0][lane]) + wv;
            float zs = bias_z;
            #pragma unroll
            for (int wp = 0; wp < 8; ++wp) zs += pz[wp * 512];
            zsig_w = sigmoidf_(zs);
        }
        f32x4 ac = zero4();                          // candidate x-part while waiting
        ac = MFMA(xf[0], wfc[0], ac);
        ac = MFMA(xf[1], wfc[1], ac);

        // ================= phase 2: c, h update =================
        {
            uintx4 q[4][4];
            poll_load(rb, (uint)(t + 1), q);         // rh(t): tags >= t+1
            #pragma unroll
            for (int s = 0; s < 4; ++s) {
                const bf16x8 hi = hi_frag4(q[s]);
                const bf16x8 lo = lo_frag4(q[s]);
                ac = MFMA(hi, wfc[s + 2], ac);
                ac = MFMA(lo, wfc[s + 2], ac);
            }
        }
        lds_acc2[wv][lane] = ac;
        __syncthreads();                             // phase-2 hand-off
        if (wv < 4) {
            const float* pc = ((const float*)&lds_acc2[0][lane]) + wv;
            float cs = bias_c;
            #pragma unroll
            for (int wp = 0; wp < 8; ++wp) cs += pc[wp * 256];
            const float c  = tanhf_(cs);
            const float hn = (t < len_w) ? fmaf(zsig_w, c - h_w, h_w) : h_w;
            h_w = hn;
            st_state(&hp2[gi_w], pack_hl(hn), (uint)(t + 1));   // critical path first
            __builtin_nontemporal_store(hn, &out[(size_t)t * BN + gi_w]);
            if (t == T_STEPS - 1)
                __builtin_nontemporal_store(hn, &out[(size_t)T_STEPS * BN + gi_w]);
        }
        az = zero4(); ar = zero4();                  // next-step x while producers publish
        if (t + 1 < T_STEPS) {
            const float* x_t = x + (size_t)(t + 1) * B_SZ * NINP;
            #pragma unroll
            for (int s = 0; s < 2; ++s) {
                const int k = (wv + 8 * s) * 32;
                xf[s] = cvt8(x_t + arow * NINP + k + q8);
                az = MFMA(xf[s], wfz[s], az);
                ar = MFMA(xf[s], wfr[s], ar);
            }
        }
    }

    // unprovable runtime guard keeps lds_pad from being stripped
    if (ld_rlx((const uint*)hp2 + 1) == 0xDEADBEEFu)
        out[0] = (float)lds_pad[tid & 1023];
}

// ws_size probe: no-op; gridDim.x = ws_size_in_MB + 1 (read from rocprof dims).
__global__ void gru_ws_probe_mb(float* p) {
    if (blockIdx.x == 0xFFFFFFFFu) p[0] = 0.f;
}

extern "C" void kernel_launch(void* const* d_in, const int* in_sizes, int n_in,
                              void* d_out, int out_size, void* d_ws, size_t ws_size,
                              hipStream_t stream) {
    const float* x   = (const float*)d_in[0];
    const float* h0  = (const float*)d_in[1];
    const float* Wiz = (const float*)d_in[2];  const float* biz = (const float*)d_in[3];
    const float* Wir = (const float*)d_in[4];  const float* bir = (const float*)d_in[5];
    const float* Wih = (const float*)d_in[6];  const float* bih = (const float*)d_in[7];
    const float* Whz = (const float*)d_in[8];  const float* bhz = (const float*)d_in[9];
    const float* Whr = (const float*)d_in[10]; const float* bhr = (const float*)d_in[11];
    const float* Whh = (const float*)d_in[12]; const float* bhh = (const float*)d_in[13];
    const void*  lengths = d_in[14];
    float* out = (float*)d_out;
    char*  ws  = (char*)d_ws;

    size_t mb = ws_size >> 20; if (mb > 2048) mb = 2048;
    gru_ws_probe_mb<<<dim3((uint)mb + 1), 64, 0, stream>>>((float*)d_ws);
    if (ws_size < (size_t)WS_NEED) return;

    ushort* wcomb = (ushort*)ws;
    float*  bsum  = (float*)(ws + WS_BSUM);
    ull*    hp2   = (ull*)(ws + WS_HP2);
    ull*    rhp2  = (ull*)(ws + WS_RHP2);

    prep_w<<<2304, 256, 0, stream>>>(Wiz, Wir, Wih, Whz, Whr, Whh, wcomb);
    prep_misc<<<257, 256, 0, stream>>>(h0, biz, bir, bih, bhz, bhr, bhh, hp2, rhp2, bsum);
    gru_persist<<<256, 512, 0, stream>>>(x, h0, lengths, wcomb, bsum,
                                         hp2, rhp2, out);
}